// Round 8
// baseline (6699.741 us; speedup 1.0000x reference)
//
#include <hip/hip_runtime.h>
#include <hip/hip_cooperative_groups.h>
#include <math.h>

namespace cg = cooperative_groups;

#define NR 8192
#define DDIM 128

static constexpr float LOG_AB2 = -13.0f;                  // -log2(8192)
static constexpr float OFF2    = -28.853900817779268f;    // -(1.0)*20*log2e constant shift
static constexpr float C8      = 0.11315255222658537f;    // (20/255)*log2e
static constexpr float DQK8    = 1.0f / 255.0f;
// RBF scale constants in log2 domain: -log2e/(2 s^2)
static constexpr float E1 = -0.7213475204444817f;
static constexpr float E2 = -0.18033688011112043f;
static constexpr float E3 = -0.045084220027780107f;
static constexpr float E4 = -0.011271055006945027f;
static constexpr float E5 = -0.0028177637517362567f;

typedef __attribute__((ext_vector_type(8))) short  s16x8;
typedef __attribute__((ext_vector_type(4))) float  f32x4;

#if defined(__has_builtin)
#if __has_builtin(__builtin_amdgcn_exp2f)
#define EX2_IMPL(x) __builtin_amdgcn_exp2f(x)
#endif
#endif
#ifndef EX2_IMPL
extern "C" __device__ float __ocml_native_exp2_f32(float);
#define EX2_IMPL(x) __ocml_native_exp2_f32(x)
#endif
__device__ inline float ex2(float x) { return EX2_IMPL(x); }

typedef const unsigned int __attribute__((address_space(1)))* gas_ptr;
typedef unsigned int __attribute__((address_space(3)))*       las_ptr;
__device__ inline void gload16(const void* g, void* l) {
    __builtin_amdgcn_global_load_lds((gas_ptr)g, (las_ptr)l, 16, 0, 0);
}

__device__ inline unsigned short bf16rn(float f) {
    const unsigned u = __float_as_uint(f);
    return (unsigned short)((u + 0x7FFFu + ((u >> 16) & 1u)) >> 16);
}

// ---------------- f32 -> (hi, lo) bf16 planes ----------------
__global__ __launch_bounds__(256) void conv_k(const float* __restrict__ X,
                                              unsigned short* __restrict__ hi,
                                              unsigned short* __restrict__ lo) {
    const int i = blockIdx.x * 1024 + threadIdx.x * 4;
    const float4 v = *reinterpret_cast<const float4*>(&X[i]);
    const float f[4] = {v.x, v.y, v.z, v.w};
    ushort4 h, l;
    unsigned short hh[4], ll[4];
#pragma unroll
    for (int j = 0; j < 4; ++j) {
        const unsigned short a = bf16rn(f[j]);
        const float hf = __uint_as_float((unsigned)a << 16);
        hh[j] = a;
        ll[j] = bf16rn(f[j] - hf);
    }
    h.x = hh[0]; h.y = hh[1]; h.z = hh[2]; h.w = hh[3];
    l.x = ll[0]; l.y = ll[1]; l.z = ll[2]; l.w = ll[3];
    *reinterpret_cast<ushort4*>(&hi[i]) = h;
    *reinterpret_cast<ushort4*>(&lo[i]) = l;
}

// ---------------- row squared-norms ----------------
__global__ __launch_bounds__(256) void rownorm_k(const float* __restrict__ X,
                                                 float* __restrict__ nrm) {
    const int lane = threadIdx.x & 63;
    const int w    = threadIdx.x >> 6;
    const int row  = blockIdx.x * 4 + w;
    const float2 v = *reinterpret_cast<const float2*>(&X[(size_t)row * DDIM + lane * 2]);
    float s = v.x * v.x + v.y * v.y;
#pragma unroll
    for (int off = 32; off; off >>= 1) s += __shfl_xor(s, off);
    if (lane == 0) nrm[row] = s;
}

// ---------------- MFMA split-bf16 GEMM + multi-scale RBF ----------------
// global_load_lds staging with pre-swizzled source (G21): LDS row = 128 B =
// 8 units of 16 B; physical unit up at row r holds logical unit up^(r&7),
// logical unit u = plane(u>>2: H/L) * 4 + kseg(u&3). Read applies same XOR.
// MODE 0: full 64x64 grid (X vs Y), store uint8 K.
// MODE 1: triangular 2080 x 2 grid (sel: X or Y), sum only; double off-diag blocks.
template <int MODE>
__global__ __launch_bounds__(256) void gemm_mfma_k(const unsigned short* __restrict__ XH,
                                                   const unsigned short* __restrict__ XL,
                                                   const unsigned short* __restrict__ YH,
                                                   const unsigned short* __restrict__ YL,
                                                   const float* __restrict__ nxp,
                                                   const float* __restrict__ nyp,
                                                   unsigned char* __restrict__ K8,
                                                   double* __restrict__ sums) {
    int bm, bn;
    const unsigned short *AH, *AL, *BH, *BL;
    const float *na, *nb;
    if (MODE == 0) {
        bm = blockIdx.x; bn = blockIdx.y;
        AH = XH; AL = XL; BH = YH; BL = YL; na = nxp; nb = nyp;
    } else {
        const int lin = blockIdx.x;  // 0..2079 triangular (bm<=bn)
        int i = (int)((129.0f - sqrtf(16641.0f - 8.0f * (float)lin)) * 0.5f);
        while (i * 64 - i * (i - 1) / 2 > lin) --i;
        while ((i + 1) * 64 - (i + 1) * i / 2 <= lin) ++i;
        bm = i;
        bn = i + (lin - (i * 64 - i * (i - 1) / 2));
        const int sel = blockIdx.y;
        AH = BH = sel ? YH : XH;
        AL = BL = sel ? YL : XL;
        na = nb = sel ? nyp : nxp;
    }
    // combined-plane LDS: [128 rows][64 ushorts] = 16 KB each
    __shared__ unsigned short Acb[128 * 64];
    __shared__ unsigned short Bcb[128 * 64];

    const int t    = threadIdx.x;
    const int lane = t & 63;
    const int w    = t >> 6;
    const int wr   = w >> 1, wc = w & 1;      // 2x2 wave grid, 64x64 sub-tile each
    const int l15  = lane & 15, lg = lane >> 4;

    // staging lane constants: 8 rows x 8 units per 1024B call
    const int lr = lane >> 3;                 // row-within-call 0..7
    const int u  = (lane & 7) ^ lr;           // logical unit (XOR with r&7 == lr)
    const int sp = u >> 2, ss = u & 3;        // plane select, k-seg

    f32x4 acc[4][4];
#pragma unroll
    for (int mi = 0; mi < 4; ++mi)
#pragma unroll
        for (int ni = 0; ni < 4; ++ni) acc[mi][ni] = (f32x4){0.f, 0.f, 0.f, 0.f};

    // per-lane global source bases
    const unsigned short* srcA = (sp ? AL : AH) + (size_t)(bm * 128 + lr) * DDIM + ss * 8;
    const unsigned short* srcB = (sp ? BL : BH) + (size_t)(bn * 128 + lr) * DDIM + ss * 8;

    for (int kc = 0; kc < 4; ++kc) {
        if (kc) __syncthreads();
        const int ko = kc * 32;
#pragma unroll
        for (int c = 0; c < 4; ++c) {
            const int row0 = w * 32 + c * 8;   // this call stages rows [row0, row0+8)
            gload16(srcA + (size_t)row0 * DDIM + ko, &Acb[row0 * 64]);
            gload16(srcB + (size_t)row0 * DDIM + ko, &Bcb[row0 * 64]);
        }
        __syncthreads();

        s16x8 bh[4], bl[4];
#pragma unroll
        for (int ni = 0; ni < 4; ++ni) {
            const int R = wc * 64 + ni * 16 + l15;
            bh[ni] = *reinterpret_cast<const s16x8*>(&Bcb[R * 64 + ((0 + lg) ^ (R & 7)) * 8]);
            bl[ni] = *reinterpret_cast<const s16x8*>(&Bcb[R * 64 + ((4 + lg) ^ (R & 7)) * 8]);
        }
#pragma unroll
        for (int mi = 0; mi < 4; ++mi) {
            const int R = wr * 64 + mi * 16 + l15;
            const s16x8 ah = *reinterpret_cast<const s16x8*>(&Acb[R * 64 + ((0 + lg) ^ (R & 7)) * 8]);
            const s16x8 al = *reinterpret_cast<const s16x8*>(&Acb[R * 64 + ((4 + lg) ^ (R & 7)) * 8]);
#pragma unroll
            for (int ni = 0; ni < 4; ++ni) {
                acc[mi][ni] = __builtin_amdgcn_mfma_f32_16x16x32_bf16(ah, bh[ni], acc[mi][ni], 0, 0, 0);
                acc[mi][ni] = __builtin_amdgcn_mfma_f32_16x16x32_bf16(ah, bl[ni], acc[mi][ni], 0, 0, 0);
                acc[mi][ni] = __builtin_amdgcn_mfma_f32_16x16x32_bf16(al, bh[ni], acc[mi][ni], 0, 0, 0);
            }
        }
    }

    // epilogue; C/D layout: col = lane&15, row = (lane>>4)*4 + j  [HW-verified]
    const int mBase = bm * 128 + wr * 64;
    const int nBase = bn * 128 + wc * 64;
    float nbv[4];
#pragma unroll
    for (int ni = 0; ni < 4; ++ni) nbv[ni] = nb[nBase + ni * 16 + l15];

    if (MODE == 0) {
#pragma unroll
        for (int mi = 0; mi < 4; ++mi) {
#pragma unroll
            for (int j = 0; j < 4; ++j) {
                const int m = mBase + mi * 16 + lg * 4 + j;
                const float nav = na[m];
                unsigned char* krow = &K8[(size_t)m * NR + nBase + l15];
#pragma unroll
                for (int ni = 0; ni < 4; ++ni) {
                    float d2 = fmaf(-2.f, acc[mi][ni][j], nav + nbv[ni]);
                    d2 = fmaxf(d2, 0.f);
                    const float kv = 0.2f * (ex2(d2 * E1) + ex2(d2 * E2) + ex2(d2 * E3) +
                                             ex2(d2 * E4) + ex2(d2 * E5));
                    krow[ni * 16] = (unsigned char)__float2uint_rn(kv * 255.f);
                }
            }
        }
    } else {
        double lsum = 0.0;
#pragma unroll
        for (int mi = 0; mi < 4; ++mi) {
#pragma unroll
            for (int j = 0; j < 4; ++j) {
                const int m = mBase + mi * 16 + lg * 4 + j;
                const float nav = na[m];
                float rs = 0.f;
#pragma unroll
                for (int ni = 0; ni < 4; ++ni) {
                    float d2 = fmaf(-2.f, acc[mi][ni][j], nav + nbv[ni]);
                    d2 = fmaxf(d2, 0.f);
                    rs += 0.2f * (ex2(d2 * E1) + ex2(d2 * E2) + ex2(d2 * E3) +
                                  ex2(d2 * E4) + ex2(d2 * E5));
                }
                lsum += (double)rs;
            }
        }
        if (bn > bm) lsum *= 2.0;
#pragma unroll
        for (int o = 32; o; o >>= 1) lsum += __shfl_xor(lsum, o);
        if (lane == 0) atomicAdd(&sums[1 + blockIdx.y], lsum);
    }
}

// log_v initial state: exact log_v=0 -> stored = OFF2
__global__ __launch_bounds__(256) void init_lv_k(float* __restrict__ log_v) {
    log_v[blockIdx.x * 256 + threadIdx.x] = OFF2;
}

// ---------------- standalone Sinkhorn phase kernels (fallback path) ----------------
__global__ __launch_bounds__(256) void sink_row_k(const unsigned char* __restrict__ K8,
                                                  const float* __restrict__ log_v,
                                                  float* __restrict__ log_u) {
    __shared__ float red[4][8];
    const int t  = threadIdx.x;
    const int r0 = blockIdx.x * 8;
    const float4* Lv4 = reinterpret_cast<const float4*>(log_v);
    float s[8];
#pragma unroll
    for (int r = 0; r < 8; ++r) s[r] = 0.f;
#pragma unroll
    for (int p = 0; p < 2; ++p) {
        const int g = t + p * 256;
        const float4 l0 = Lv4[4 * g + 0];
        const float4 l1 = Lv4[4 * g + 1];
        const float4 l2 = Lv4[4 * g + 2];
        const float4 l3 = Lv4[4 * g + 3];
        const float lvv[16] = {l0.x, l0.y, l0.z, l0.w, l1.x, l1.y, l1.z, l1.w,
                               l2.x, l2.y, l2.z, l2.w, l3.x, l3.y, l3.z, l3.w};
        const uint4* col = reinterpret_cast<const uint4*>(K8 + (size_t)r0 * NR) + g;
#pragma unroll
        for (int r = 0; r < 8; ++r) {
            const uint4 wq = col[(size_t)r * 512];
            const unsigned wd[4] = {wq.x, wq.y, wq.z, wq.w};
#pragma unroll
            for (int d = 0; d < 4; ++d) {
                const unsigned a = wd[d];
                s[r] += ex2(fmaf((float)(a & 255u),          C8, lvv[4 * d + 0]))
                      + ex2(fmaf((float)((a >> 8) & 255u),   C8, lvv[4 * d + 1]))
                      + ex2(fmaf((float)((a >> 16) & 255u),  C8, lvv[4 * d + 2]))
                      + ex2(fmaf((float)(a >> 24),           C8, lvv[4 * d + 3]));
            }
        }
    }
    const int lane = t & 63, wv = t >> 6;
#pragma unroll
    for (int r = 0; r < 8; ++r) {
        float v = s[r];
#pragma unroll
        for (int o = 32; o; o >>= 1) v += __shfl_xor(v, o);
        if (lane == 0) red[wv][r] = v;
    }
    __syncthreads();
    if (t < 8) {
        const float stot = (red[0][t] + red[1][t]) + (red[2][t] + red[3][t]);
        log_u[r0 + t] = LOG_AB2 - __log2f(stot) + OFF2;
    }
}

__global__ __launch_bounds__(256) void sink_colp_k(const unsigned char* __restrict__ K8,
                                                   const float* __restrict__ log_u,
                                                   float* __restrict__ ps) {
    const int t   = threadIdx.x;
    const int cg4 = blockIdx.x * 256 + t;
    const int rc  = blockIdx.y;
    const uint4* base = reinterpret_cast<const uint4*>(K8) + (size_t)rc * 32 * 512 + cg4;
    const float* lu = log_u + rc * 32;
    float s16[16];
#pragma unroll
    for (int e = 0; e < 16; ++e) s16[e] = 0.f;
#pragma unroll 4
    for (int r = 0; r < 32; ++r) {
        const uint4 wq = base[(size_t)r * 512];
        const float lur = lu[r];
        const unsigned wd[4] = {wq.x, wq.y, wq.z, wq.w};
#pragma unroll
        for (int d = 0; d < 4; ++d) {
            const unsigned a = wd[d];
            s16[4 * d + 0] += ex2(fmaf((float)(a & 255u),         C8, lur));
            s16[4 * d + 1] += ex2(fmaf((float)((a >> 8) & 255u),  C8, lur));
            s16[4 * d + 2] += ex2(fmaf((float)((a >> 16) & 255u), C8, lur));
            s16[4 * d + 3] += ex2(fmaf((float)(a >> 24),          C8, lur));
        }
    }
    float4* pv = reinterpret_cast<float4*>(ps + (size_t)rc * NR + cg4 * 16);
#pragma unroll
    for (int d = 0; d < 4; ++d)
        pv[d] = {s16[4 * d + 0], s16[4 * d + 1], s16[4 * d + 2], s16[4 * d + 3]};
}

__global__ __launch_bounds__(256) void sink_combine_k(const float* __restrict__ ps,
                                                      float* __restrict__ log_v) {
    __shared__ float red[4][64];
    const int lane = threadIdx.x & 63;
    const int grp  = threadIdx.x >> 6;
    const int col  = blockIdx.x * 64 + lane;
    float s = 0.f;
#pragma unroll 8
    for (int c = grp * 64; c < grp * 64 + 64; ++c) s += ps[(size_t)c * NR + col];
    red[grp][lane] = s;
    __syncthreads();
    if (grp == 0) {
        const float stot = (red[0][lane] + red[1][lane]) + (red[2][lane] + red[3][lane]);
        log_v[col] = LOG_AB2 - __log2f(stot) + OFF2;
    }
}

// ---------------- persistent cooperative Sinkhorn: 512 blocks, 30 iters ----------------
__global__ __launch_bounds__(256) void sink_loop_k(const unsigned char* __restrict__ K8,
                                                   float* __restrict__ log_u,
                                                   float* __restrict__ log_v,
                                                   float* __restrict__ ps) {
    cg::grid_group grid = cg::this_grid();
    __shared__ float redr[4][8];
    __shared__ float redc[4][64];
    const int bid  = blockIdx.x;   // 0..511
    const int t    = threadIdx.x;
    const int lane = t & 63;
    const int wv   = t >> 6;

    for (int it = 0; it < 30; ++it) {
        // ---- row phase: 2 x 8 rows per block ----
#pragma unroll 1
        for (int h = 0; h < 2; ++h) {
            const int r0 = bid * 16 + h * 8;
            const float4* Lv4 = reinterpret_cast<const float4*>(log_v);
            float s[8];
#pragma unroll
            for (int r = 0; r < 8; ++r) s[r] = 0.f;
#pragma unroll
            for (int p = 0; p < 2; ++p) {
                const int g = t + p * 256;
                const float4 l0 = Lv4[4 * g + 0];
                const float4 l1 = Lv4[4 * g + 1];
                const float4 l2 = Lv4[4 * g + 2];
                const float4 l3 = Lv4[4 * g + 3];
                const float lvv[16] = {l0.x, l0.y, l0.z, l0.w, l1.x, l1.y, l1.z, l1.w,
                                       l2.x, l2.y, l2.z, l2.w, l3.x, l3.y, l3.z, l3.w};
                const uint4* col = reinterpret_cast<const uint4*>(K8 + (size_t)r0 * NR) + g;
#pragma unroll
                for (int r = 0; r < 8; ++r) {
                    const uint4 wq = col[(size_t)r * 512];
                    const unsigned wd[4] = {wq.x, wq.y, wq.z, wq.w};
#pragma unroll
                    for (int d = 0; d < 4; ++d) {
                        const unsigned a = wd[d];
                        s[r] += ex2(fmaf((float)(a & 255u),          C8, lvv[4 * d + 0]))
                              + ex2(fmaf((float)((a >> 8) & 255u),   C8, lvv[4 * d + 1]))
                              + ex2(fmaf((float)((a >> 16) & 255u),  C8, lvv[4 * d + 2]))
                              + ex2(fmaf((float)(a >> 24),           C8, lvv[4 * d + 3]));
                    }
                }
            }
#pragma unroll
            for (int r = 0; r < 8; ++r) {
                float v = s[r];
#pragma unroll
                for (int o = 32; o; o >>= 1) v += __shfl_xor(v, o);
                if (lane == 0) redr[wv][r] = v;
            }
            __syncthreads();
            if (t < 8) {
                const float stot = (redr[0][t] + redr[1][t]) + (redr[2][t] + redr[3][t]);
                log_u[r0 + t] = LOG_AB2 - __log2f(stot) + OFF2;
            }
            __syncthreads();
        }
        grid.sync();

        // ---- col partial phase: 512 blocks, 256 chunks x 32 rows ----
        {
            const int cg4 = (bid & 1) * 256 + t;
            const int rc  = bid >> 1;
            const uint4* base = reinterpret_cast<const uint4*>(K8) + (size_t)rc * 32 * 512 + cg4;
            const float* lu = log_u + rc * 32;
            float s16[16];
#pragma unroll
            for (int e = 0; e < 16; ++e) s16[e] = 0.f;
#pragma unroll 4
            for (int r = 0; r < 32; ++r) {
                const uint4 wq = base[(size_t)r * 512];
                const float lur = lu[r];
                const unsigned wd[4] = {wq.x, wq.y, wq.z, wq.w};
#pragma unroll
                for (int d = 0; d < 4; ++d) {
                    const unsigned a = wd[d];
                    s16[4 * d + 0] += ex2(fmaf((float)(a & 255u),         C8, lur));
                    s16[4 * d + 1] += ex2(fmaf((float)((a >> 8) & 255u),  C8, lur));
                    s16[4 * d + 2] += ex2(fmaf((float)((a >> 16) & 255u), C8, lur));
                    s16[4 * d + 3] += ex2(fmaf((float)(a >> 24),          C8, lur));
                }
            }
            float4* pv = reinterpret_cast<float4*>(ps + (size_t)rc * NR + cg4 * 16);
#pragma unroll
            for (int d = 0; d < 4; ++d)
                pv[d] = {s16[4 * d + 0], s16[4 * d + 1], s16[4 * d + 2], s16[4 * d + 3]};
        }
        grid.sync();

        // ---- combine phase: blocks 0..127 ----
        if (bid < 128) {
            const int col = bid * 64 + lane;
            float s = 0.f;
#pragma unroll 8
            for (int c = wv * 64; c < wv * 64 + 64; ++c) s += ps[(size_t)c * NR + col];
            redc[wv][lane] = s;
            __syncthreads();
            if (wv == 0) {
                const float stot = (redc[0][lane] + redc[1][lane]) + (redc[2][lane] + redc[3][lane]);
                log_v[col] = LOG_AB2 - __log2f(stot) + OFF2;
            }
            __syncthreads();
        }
        grid.sync();
    }
}

// ---------------- final sum(Gamma * Kxy); scaled by DQK8 in finalize ----------------
__global__ __launch_bounds__(256) void gamma_sum_k(const unsigned char* __restrict__ K8,
                                                   const float* __restrict__ log_u,
                                                   const float* __restrict__ log_v,
                                                   double* __restrict__ S) {
    const int t   = threadIdx.x;
    const int cg4 = blockIdx.x * 256 + t;
    const int rc  = blockIdx.y;
    float lvp[16];
#pragma unroll
    for (int e = 0; e < 16; ++e) lvp[e] = log_v[cg4 * 16 + e] - OFF2;
    const uint4* base = reinterpret_cast<const uint4*>(K8) + (size_t)rc * 32 * 512 + cg4;
    const float* lu = log_u + rc * 32;
    double acc = 0.0;
#pragma unroll 4
    for (int r = 0; r < 32; ++r) {
        const uint4 w = base[(size_t)r * 512];
        const float lur = lu[r];
        const unsigned wd[4] = {w.x, w.y, w.z, w.w};
        float rs = 0.f;
#pragma unroll
        for (int d = 0; d < 4; ++d) {
            const unsigned a = wd[d];
            const float q0 = (float)(a & 255u);
            const float q1 = (float)((a >> 8) & 255u);
            const float q2 = (float)((a >> 16) & 255u);
            const float q3 = (float)(a >> 24);
            rs = fmaf(ex2(fmaf(q0, C8, lur + lvp[4 * d + 0])), q0, rs);
            rs = fmaf(ex2(fmaf(q1, C8, lur + lvp[4 * d + 1])), q1, rs);
            rs = fmaf(ex2(fmaf(q2, C8, lur + lvp[4 * d + 2])), q2, rs);
            rs = fmaf(ex2(fmaf(q3, C8, lur + lvp[4 * d + 3])), q3, rs);
        }
        acc += (double)rs;
    }
#pragma unroll
    for (int o = 32; o; o >>= 1) acc += __shfl_xor(acc, o);
    if ((t & 63) == 0) atomicAdd(S, acc);
}

__global__ void finalize_k(const double* __restrict__ scal, float* __restrict__ out) {
    const double inv = 1.0 / (8192.0 * 8192.0);
    out[0] = (float)(scal[1] * inv + scal[2] * inv - 2.0 * (double)DQK8 * scal[3]);
}

extern "C" void kernel_launch(void* const* d_in, const int* in_sizes, int n_in,
                              void* d_out, int out_size, void* d_ws, size_t ws_size,
                              hipStream_t stream) {
    const float* X = (const float*)d_in[0];
    const float* Y = (const float*)d_in[1];

    // ---- workspace layout ----
    char* ws = (char*)d_ws;
    unsigned char* K8 = (unsigned char*)ws;               // 67108864 B
    float* nx    = (float*)(ws + 67108864);               // 32 KB each
    float* ny    = nx + NR;
    float* log_u = ny + NR;
    float* log_v = log_u + NR;
    char*  scal  = (char*)(log_v + NR);                   // 512 B
    double* scal_d = (double*)scal;                       // [1]=kxx, [2]=kyy, [3]=S
    float* ps = (float*)(scal + 512);                     // 8 MB
    unsigned short* XH = (unsigned short*)(ws + 75629056);  // 2 MB each
    unsigned short* XL = XH + NR * DDIM;
    unsigned short* YH = XL + NR * DDIM;
    unsigned short* YL = YH + NR * DDIM;
    const size_t needed = 75629056 + 4 * (size_t)NR * DDIM * 2;
    if (ws_size < needed) return;  // clean absmax failure instead of a GPU fault

    hipMemsetAsync(scal, 0, 512, stream);  // sums = 0

    conv_k<<<NR * DDIM / 1024, 256, 0, stream>>>(X, XH, XL);
    conv_k<<<NR * DDIM / 1024, 256, 0, stream>>>(Y, YH, YL);
    rownorm_k<<<NR / 4, 256, 0, stream>>>(X, nx);
    rownorm_k<<<NR / 4, 256, 0, stream>>>(Y, ny);

    gemm_mfma_k<0><<<dim3(64, 64), 256, 0, stream>>>(XH, XL, YH, YL, nx, ny, K8, scal_d);
    gemm_mfma_k<1><<<dim3(2080, 2), 256, 0, stream>>>(XH, XL, YH, YL, nx, ny, nullptr, scal_d);

    init_lv_k<<<NR / 256, 256, 0, stream>>>(log_v);

    {
        void* args[] = {(void*)&K8, (void*)&log_u, (void*)&log_v, (void*)&ps};
        hipError_t err = hipLaunchCooperativeKernel((const void*)sink_loop_k, dim3(512),
                                                    dim3(256), args, 0, stream);
        if (err != hipSuccess) {
            // fallback: proven 3-kernel-per-iteration path
            for (int it = 0; it < 30; ++it) {
                sink_row_k<<<NR / 8, 256, 0, stream>>>(K8, log_v, log_u);
                sink_colp_k<<<dim3(2, 256), 256, 0, stream>>>(K8, log_u, ps);
                sink_combine_k<<<128, 256, 0, stream>>>(ps, log_v);
            }
        }
    }

    gamma_sum_k<<<dim3(2, 256), 256, 0, stream>>>(K8, log_u, log_v, scal_d + 3);
    finalize_k<<<1, 1, 0, stream>>>(scal_d, (float*)d_out);
}

// Round 10
// 1571.637 us; speedup vs baseline: 4.2629x; 4.2629x over previous
//
#include <hip/hip_runtime.h>
#include <math.h>

#define NR 8192
#define DDIM 128

static constexpr float LOG_AB2 = -13.0f;                  // -log2(8192)
static constexpr float OFF2    = -28.853900817779268f;    // -(1.0)*20*log2e constant shift
static constexpr float C8      = 0.11315255222658537f;    // (20/255)*log2e
static constexpr float DQK8    = 1.0f / 255.0f;
// RBF scale constants in log2 domain: -log2e/(2 s^2)
static constexpr float E1 = -0.7213475204444817f;
static constexpr float E2 = -0.18033688011112043f;
static constexpr float E3 = -0.045084220027780107f;
static constexpr float E4 = -0.011271055006945027f;
static constexpr float E5 = -0.0028177637517362567f;

typedef __attribute__((ext_vector_type(8))) _Float16 f16x8;
typedef __attribute__((ext_vector_type(4))) float    f32x4;

#if defined(__has_builtin)
#if __has_builtin(__builtin_amdgcn_exp2f)
#define EX2_IMPL(x) __builtin_amdgcn_exp2f(x)
#endif
#endif
#ifndef EX2_IMPL
extern "C" __device__ float __ocml_native_exp2_f32(float);
#define EX2_IMPL(x) __ocml_native_exp2_f32(x)
#endif
__device__ inline float ex2(float x) { return EX2_IMPL(x); }

typedef const unsigned int __attribute__((address_space(1)))* gas_ptr;
typedef unsigned int __attribute__((address_space(3)))*       las_ptr;
__device__ inline void gload16(const void* g, void* l) {
    __builtin_amdgcn_global_load_lds((gas_ptr)g, (las_ptr)l, 16, 0, 0);
}

__device__ inline unsigned short f2h(float f) {
    return __builtin_bit_cast(unsigned short, (_Float16)f);
}

// ---------------- f32 -> fp16 plane ----------------
__global__ __launch_bounds__(256) void convh_k(const float* __restrict__ X,
                                               unsigned short* __restrict__ H) {
    const int i = blockIdx.x * 1024 + threadIdx.x * 4;
    const float4 v = *reinterpret_cast<const float4*>(&X[i]);
    ushort4 h;
    h.x = f2h(v.x);
    h.y = f2h(v.y);
    h.z = f2h(v.z);
    h.w = f2h(v.w);
    *reinterpret_cast<ushort4*>(&H[i]) = h;
}

// ---------------- row squared-norms (exact f32) ----------------
__global__ __launch_bounds__(256) void rownorm_k(const float* __restrict__ X,
                                                 float* __restrict__ nrm) {
    const int lane = threadIdx.x & 63;
    const int w    = threadIdx.x >> 6;
    const int row  = blockIdx.x * 4 + w;
    const float2 v = *reinterpret_cast<const float2*>(&X[(size_t)row * DDIM + lane * 2]);
    float s = v.x * v.x + v.y * v.y;
#pragma unroll
    for (int off = 32; off; off >>= 1) s += __shfl_xor(s, off);
    if (lane == 0) nrm[row] = s;
}

// ---------------- fp16 MFMA GEMM + multi-scale RBF ----------------
// Combined LDS tile: 128-B rows = 8 units of 16 B; units 0-3 = A row (32 halfs),
// units 4-7 = B row. Physical unit p at row r holds logical unit p^(r&7) (G21:
// linear gload dest + inverse-swizzled per-lane SOURCE + swizzled read).
// MODE 0: full 64x64 grid (X vs Y), store uint8 K.
// MODE 1: triangular 2080 x 2 grid (sel: X or Y), sum only; double off-diag blocks.
template <int MODE>
__global__ __launch_bounds__(256) void gemm_mfma_k(const unsigned short* __restrict__ XF,
                                                   const unsigned short* __restrict__ YF,
                                                   const float* __restrict__ nxp,
                                                   const float* __restrict__ nyp,
                                                   unsigned char* __restrict__ K8,
                                                   double* __restrict__ sums) {
    int bm, bn;
    const unsigned short *A, *B;
    const float *na, *nb;
    if (MODE == 0) {
        bm = blockIdx.x; bn = blockIdx.y;
        A = XF; B = YF; na = nxp; nb = nyp;
    } else {
        const int lin = blockIdx.x;  // 0..2079 triangular (bm<=bn)
        int i = (int)((129.0f - sqrtf(16641.0f - 8.0f * (float)lin)) * 0.5f);
        while (i * 64 - i * (i - 1) / 2 > lin) --i;
        while ((i + 1) * 64 - (i + 1) * i / 2 <= lin) ++i;
        bm = i;
        bn = i + (lin - (i * 64 - i * (i - 1) / 2));
        const int sel = blockIdx.y;
        A = B = sel ? YF : XF;
        na = nb = sel ? nyp : nxp;
    }
    __shared__ unsigned short Tile[128 * 64];   // 16 KB

    const int t    = threadIdx.x;
    const int lane = t & 63;
    const int w    = t >> 6;
    const int wr   = w >> 1, wc = w & 1;      // 2x2 wave grid, 64x64 sub-tile each
    const int l15  = lane & 15, lg = lane >> 4;

    // staging lane constants: 8 rows x 8 units per 1024B call
    const int lr = lane >> 3;                 // row-within-call 0..7
    const int u  = (lane & 7) ^ lr;           // logical unit
    const int ss = u & 3;                     // k-seg within matrix

    f32x4 acc[4][4];
#pragma unroll
    for (int mi = 0; mi < 4; ++mi)
#pragma unroll
        for (int ni = 0; ni < 4; ++ni) acc[mi][ni] = (f32x4){0.f, 0.f, 0.f, 0.f};

    // per-lane global source base: A-tile rows for u<4, B-tile rows for u>=4
    const unsigned short* src = (u < 4)
        ? A + (size_t)(bm * 128 + lr) * DDIM + ss * 8
        : B + (size_t)(bn * 128 + lr) * DDIM + ss * 8;

    for (int kc = 0; kc < 4; ++kc) {
        if (kc) __syncthreads();
        const int ko = kc * 32;
#pragma unroll
        for (int c = 0; c < 4; ++c) {
            const int row0 = w * 32 + c * 8;   // this call stages rows [row0, row0+8)
            gload16(src + (size_t)row0 * DDIM + ko, &Tile[row0 * 64]);
        }
        __syncthreads();

        f16x8 bf[4];
#pragma unroll
        for (int ni = 0; ni < 4; ++ni) {
            const int R = wc * 64 + ni * 16 + l15;
            bf[ni] = *reinterpret_cast<const f16x8*>(&Tile[R * 64 + ((4 + lg) ^ (R & 7)) * 8]);
        }
#pragma unroll
        for (int mi = 0; mi < 4; ++mi) {
            const int R = wr * 64 + mi * 16 + l15;
            const f16x8 af = *reinterpret_cast<const f16x8*>(&Tile[R * 64 + (lg ^ (R & 7)) * 8]);
#pragma unroll
            for (int ni = 0; ni < 4; ++ni)
                acc[mi][ni] = __builtin_amdgcn_mfma_f32_16x16x32_f16(af, bf[ni], acc[mi][ni], 0, 0, 0);
        }
    }

    // epilogue; C/D layout: col = lane&15, row = (lane>>4)*4 + j  [HW-verified]
    const int mBase = bm * 128 + wr * 64;
    const int nBase = bn * 128 + wc * 64;
    float nbv[4];
#pragma unroll
    for (int ni = 0; ni < 4; ++ni) nbv[ni] = nb[nBase + ni * 16 + l15];

    if (MODE == 0) {
#pragma unroll
        for (int mi = 0; mi < 4; ++mi) {
#pragma unroll
            for (int j = 0; j < 4; ++j) {
                const int m = mBase + mi * 16 + lg * 4 + j;
                const float nav = na[m];
                unsigned char* krow = &K8[(size_t)m * NR + nBase + l15];
#pragma unroll
                for (int ni = 0; ni < 4; ++ni) {
                    float d2 = fmaf(-2.f, acc[mi][ni][j], nav + nbv[ni]);
                    d2 = fmaxf(d2, 0.f);
                    const float kv = 0.2f * (ex2(d2 * E1) + ex2(d2 * E2) + ex2(d2 * E3) +
                                             ex2(d2 * E4) + ex2(d2 * E5));
                    krow[ni * 16] = (unsigned char)__float2uint_rn(kv * 255.f);
                }
            }
        }
    } else {
        double lsum = 0.0;
#pragma unroll
        for (int mi = 0; mi < 4; ++mi) {
#pragma unroll
            for (int j = 0; j < 4; ++j) {
                const int m = mBase + mi * 16 + lg * 4 + j;
                const float nav = na[m];
                float rs = 0.f;
#pragma unroll
                for (int ni = 0; ni < 4; ++ni) {
                    float d2 = fmaf(-2.f, acc[mi][ni][j], nav + nbv[ni]);
                    d2 = fmaxf(d2, 0.f);
                    rs += 0.2f * (ex2(d2 * E1) + ex2(d2 * E2) + ex2(d2 * E3) +
                                  ex2(d2 * E4) + ex2(d2 * E5));
                }
                lsum += (double)rs;
            }
        }
        if (bn > bm) lsum *= 2.0;
#pragma unroll
        for (int o = 32; o; o >>= 1) lsum += __shfl_xor(lsum, o);
        if (lane == 0) atomicAdd(&sums[1 + blockIdx.y], lsum);
    }
}

// log_v initial state: exact log_v=0 -> stored = OFF2
__global__ __launch_bounds__(256) void init_lv_k(float* __restrict__ log_v) {
    log_v[blockIdx.x * 256 + threadIdx.x] = OFF2;
}

// ---------------- Sinkhorn row pass: 8 rows/block (proven R6 path) ----------------
__global__ __launch_bounds__(256) void sink_row_k(const unsigned char* __restrict__ K8,
                                                  const float* __restrict__ log_v,
                                                  float* __restrict__ log_u) {
    __shared__ float red[4][8];
    const int t  = threadIdx.x;
    const int r0 = blockIdx.x * 8;
    const float4* Lv4 = reinterpret_cast<const float4*>(log_v);
    float s[8];
#pragma unroll
    for (int r = 0; r < 8; ++r) s[r] = 0.f;
#pragma unroll
    for (int p = 0; p < 2; ++p) {
        const int g = t + p * 256;  // uint4 group: cols 16g..16g+15
        const float4 l0 = Lv4[4 * g + 0];
        const float4 l1 = Lv4[4 * g + 1];
        const float4 l2 = Lv4[4 * g + 2];
        const float4 l3 = Lv4[4 * g + 3];
        const float lvv[16] = {l0.x, l0.y, l0.z, l0.w, l1.x, l1.y, l1.z, l1.w,
                               l2.x, l2.y, l2.z, l2.w, l3.x, l3.y, l3.z, l3.w};
        const uint4* col = reinterpret_cast<const uint4*>(K8 + (size_t)r0 * NR) + g;
#pragma unroll
        for (int r = 0; r < 8; ++r) {
            const uint4 wq = col[(size_t)r * 512];
            const unsigned wd[4] = {wq.x, wq.y, wq.z, wq.w};
#pragma unroll
            for (int d = 0; d < 4; ++d) {
                const unsigned a = wd[d];
                s[r] += ex2(fmaf((float)(a & 255u),          C8, lvv[4 * d + 0]))
                      + ex2(fmaf((float)((a >> 8) & 255u),   C8, lvv[4 * d + 1]))
                      + ex2(fmaf((float)((a >> 16) & 255u),  C8, lvv[4 * d + 2]))
                      + ex2(fmaf((float)(a >> 24),           C8, lvv[4 * d + 3]));
            }
        }
    }
    const int lane = t & 63, wv = t >> 6;
#pragma unroll
    for (int r = 0; r < 8; ++r) {
        float v = s[r];
#pragma unroll
        for (int o = 32; o; o >>= 1) v += __shfl_xor(v, o);
        if (lane == 0) red[wv][r] = v;
    }
    __syncthreads();
    if (t < 8) {
        const float stot = (red[0][t] + red[1][t]) + (red[2][t] + red[3][t]);
        log_u[r0 + t] = LOG_AB2 - __log2f(stot) + OFF2;
    }
}

// ---------------- Sinkhorn column pass: partial sums over 32-row chunks ----------------
__global__ __launch_bounds__(256) void sink_colp_k(const unsigned char* __restrict__ K8,
                                                   const float* __restrict__ log_u,
                                                   float* __restrict__ ps) {
    const int t   = threadIdx.x;
    const int cg4 = blockIdx.x * 256 + t;
    const int rc  = blockIdx.y;
    const uint4* base = reinterpret_cast<const uint4*>(K8) + (size_t)rc * 32 * 512 + cg4;
    const float* lu = log_u + rc * 32;
    float s16[16];
#pragma unroll
    for (int e = 0; e < 16; ++e) s16[e] = 0.f;
#pragma unroll 4
    for (int r = 0; r < 32; ++r) {
        const uint4 wq = base[(size_t)r * 512];
        const float lur = lu[r];
        const unsigned wd[4] = {wq.x, wq.y, wq.z, wq.w};
#pragma unroll
        for (int d = 0; d < 4; ++d) {
            const unsigned a = wd[d];
            s16[4 * d + 0] += ex2(fmaf((float)(a & 255u),         C8, lur));
            s16[4 * d + 1] += ex2(fmaf((float)((a >> 8) & 255u),  C8, lur));
            s16[4 * d + 2] += ex2(fmaf((float)((a >> 16) & 255u), C8, lur));
            s16[4 * d + 3] += ex2(fmaf((float)(a >> 24),          C8, lur));
        }
    }
    float4* pv = reinterpret_cast<float4*>(ps + (size_t)rc * NR + cg4 * 16);
#pragma unroll
    for (int d = 0; d < 4; ++d)
        pv[d] = {s16[4 * d + 0], s16[4 * d + 1], s16[4 * d + 2], s16[4 * d + 3]};
}

__global__ __launch_bounds__(256) void sink_combine_k(const float* __restrict__ ps,
                                                      float* __restrict__ log_v) {
    __shared__ float red[4][64];
    const int lane = threadIdx.x & 63;
    const int grp  = threadIdx.x >> 6;
    const int col  = blockIdx.x * 64 + lane;
    float s = 0.f;
#pragma unroll 8
    for (int c = grp * 64; c < grp * 64 + 64; ++c) s += ps[(size_t)c * NR + col];
    red[grp][lane] = s;
    __syncthreads();
    if (grp == 0) {
        const float stot = (red[0][lane] + red[1][lane]) + (red[2][lane] + red[3][lane]);
        log_v[col] = LOG_AB2 - __log2f(stot) + OFF2;
    }
}

// ---------------- final sum(Gamma * Kxy); scaled by DQK8 in finalize ----------------
__global__ __launch_bounds__(256) void gamma_sum_k(const unsigned char* __restrict__ K8,
                                                   const float* __restrict__ log_u,
                                                   const float* __restrict__ log_v,
                                                   double* __restrict__ S) {
    const int t   = threadIdx.x;
    const int cg4 = blockIdx.x * 256 + t;
    const int rc  = blockIdx.y;
    float lvp[16];
#pragma unroll
    for (int e = 0; e < 16; ++e) lvp[e] = log_v[cg4 * 16 + e] - OFF2;
    const uint4* base = reinterpret_cast<const uint4*>(K8) + (size_t)rc * 32 * 512 + cg4;
    const float* lu = log_u + rc * 32;
    double acc = 0.0;
#pragma unroll 4
    for (int r = 0; r < 32; ++r) {
        const uint4 w = base[(size_t)r * 512];
        const float lur = lu[r];
        const unsigned wd[4] = {w.x, w.y, w.z, w.w};
        float rs = 0.f;
#pragma unroll
        for (int d = 0; d < 4; ++d) {
            const unsigned a = wd[d];
            const float q0 = (float)(a & 255u);
            const float q1 = (float)((a >> 8) & 255u);
            const float q2 = (float)((a >> 16) & 255u);
            const float q3 = (float)(a >> 24);
            rs = fmaf(ex2(fmaf(q0, C8, lur + lvp[4 * d + 0])), q0, rs);
            rs = fmaf(ex2(fmaf(q1, C8, lur + lvp[4 * d + 1])), q1, rs);
            rs = fmaf(ex2(fmaf(q2, C8, lur + lvp[4 * d + 2])), q2, rs);
            rs = fmaf(ex2(fmaf(q3, C8, lur + lvp[4 * d + 3])), q3, rs);
        }
        acc += (double)rs;
    }
#pragma unroll
    for (int o = 32; o; o >>= 1) acc += __shfl_xor(acc, o);
    if ((t & 63) == 0) atomicAdd(S, acc);
}

__global__ void finalize_k(const double* __restrict__ scal, float* __restrict__ out) {
    const double inv = 1.0 / (8192.0 * 8192.0);
    out[0] = (float)(scal[1] * inv + scal[2] * inv - 2.0 * (double)DQK8 * scal[3]);
}

extern "C" void kernel_launch(void* const* d_in, const int* in_sizes, int n_in,
                              void* d_out, int out_size, void* d_ws, size_t ws_size,
                              hipStream_t stream) {
    const float* X = (const float*)d_in[0];
    const float* Y = (const float*)d_in[1];

    // ---- workspace layout ----
    char* ws = (char*)d_ws;
    unsigned char* K8 = (unsigned char*)ws;               // 67108864 B
    float* nx    = (float*)(ws + 67108864);               // 32 KB each
    float* ny    = nx + NR;
    float* log_u = ny + NR;
    float* log_v = log_u + NR;
    char*  scal  = (char*)(log_v + NR);                   // 512 B
    double* scal_d = (double*)scal;                       // [1]=kxx, [2]=kyy, [3]=S
    float* ps = (float*)(scal + 512);                     // 8 MB
    unsigned short* XF = (unsigned short*)(ws + 75629056);  // 2 MB each
    unsigned short* YF = XF + NR * DDIM;
    const size_t needed = 75629056 + 2 * (size_t)NR * DDIM * 2;
    if (ws_size < needed) return;  // clean absmax failure instead of a GPU fault

    (void)hipMemsetAsync(scal, 0, 512, stream);  // sums = 0

    convh_k<<<NR * DDIM / 1024, 256, 0, stream>>>(X, XF);
    convh_k<<<NR * DDIM / 1024, 256, 0, stream>>>(Y, YF);
    rownorm_k<<<NR / 4, 256, 0, stream>>>(X, nx);
    rownorm_k<<<NR / 4, 256, 0, stream>>>(Y, ny);

    gemm_mfma_k<0><<<dim3(64, 64), 256, 0, stream>>>(XF, YF, nx, ny, K8, scal_d);
    gemm_mfma_k<1><<<dim3(2080, 2), 256, 0, stream>>>(XF, YF, nx, ny, nullptr, scal_d);

    init_lv_k<<<NR / 256, 256, 0, stream>>>(log_v);

    for (int it = 0; it < 30; ++it) {
        sink_row_k<<<NR / 8, 256, 0, stream>>>(K8, log_v, log_u);
        sink_colp_k<<<dim3(2, 256), 256, 0, stream>>>(K8, log_u, ps);
        sink_combine_k<<<128, 256, 0, stream>>>(ps, log_v);
    }

    gamma_sum_k<<<dim3(2, 256), 256, 0, stream>>>(K8, log_u, log_v, scal_d + 3);
    finalize_k<<<1, 1, 0, stream>>>(scal_d, (float*)d_out);
}